// Round 3
// baseline (139.864 us; speedup 1.0000x reference)
//
#include <hip/hip_runtime.h>
#include <hip/hip_bf16.h>

// VQ-VAE quantize: x[32,64,64,64] NCHW fp32, codebook[512,64] fp32.
// out[0] = 1.25*SSD/8388608 ; out[1..] = codebook[argmin] in NCHW.
// R3: 3-kernel split. k0: codebook -> bf16 MFMA-fragment layout in ws + hn2.
// k1: per-128-row-tile argmin via MFMA (codebook quarters double-buffered,
//     64B/thread reg staging, 1 barrier/quarter), writes idx + loss partials.
// k2: gather + LDS transpose + coalesced NCHW store; block0 finalizes loss.

typedef __attribute__((ext_vector_type(8))) __bf16 bf16x8;
typedef __attribute__((ext_vector_type(4))) float f32x4;

// ---- d_ws layout (bytes) ----
#define WS_CBF   0        // 65536: bf16 codebook fragments (32 ctiles x 2 kk x 1024B)
#define WS_HN2   65536    // 2048:  -0.5*||c||^2 f32[512]
#define WS_RED   67584    // 4096:  per-block loss partials f32[1024]
#define WS_IDX   73728    // 262144: ushort idx[131072]

__device__ __forceinline__ unsigned f2b1(float f) {
  unsigned u = __float_as_uint(f);
  return (u + 0x7FFFu + ((u >> 16) & 1)) >> 16;   // RNE float->bf16 bits
}
__device__ __forceinline__ unsigned pack2(float lo, float hi) {
  return f2b1(lo) | (f2b1(hi) << 16);
}
__device__ __forceinline__ int swz(int row) {    // XOR swizzle, 16B granules
  return ((row & 7) ^ ((row >> 4) & 7)) << 4;
}

// ================= k0: codebook prep =================
__global__ void vq_prep(const float* __restrict__ cb, char* __restrict__ ws) {
  const int n = blockIdx.x * 128 + threadIdx.x;   // code 0..511
  const float4* cb4 = (const float4*)cb;
  float4 f[16];
  #pragma unroll
  for (int j = 0; j < 16; ++j) f[j] = cb4[(n << 4) + j];
  float s = 0.f;
  #pragma unroll
  for (int j = 0; j < 16; ++j)
    s += f[j].x * f[j].x + f[j].y * f[j].y + f[j].z * f[j].z + f[j].w * f[j].w;
  ((float*)(ws + WS_HN2))[n] = -0.5f * s;
  const int ct = n >> 4, col = n & 15;
  #pragma unroll
  for (int kk = 0; kk < 2; ++kk) {
    #pragma unroll
    for (int g = 0; g < 4; ++g) {
      float4 a = f[kk * 8 + g * 2], b = f[kk * 8 + g * 2 + 1];
      uint4 u = {pack2(a.x, a.y), pack2(a.z, a.w), pack2(b.x, b.y), pack2(b.z, b.w)};
      // fragment: lane = (g<<4)|col holds code=ct*16+col, k=kk*32+g*8+e
      *(uint4*)(ws + WS_CBF + (((ct << 1) + kk) << 10) + ((g << 4) | col) * 16) = u;
    }
  }
}

// ================= k1: argmin + loss partials =================
#define K1_XA  0        // 16384: bf16 x-tile [128][64] swizzled
#define K1_CB0 16384    // 16384: codebook quarter buf 0 (fragment-linear)
#define K1_CB1 32768    // 16384: quarter buf 1
#define K1_HN  49152    // 2048:  hn2 f32[512]
#define K1_RED 51200    // 16
#define K1_SZ  51264

__global__ void __launch_bounds__(256, 3)
vq_argmin(const float* __restrict__ x, char* __restrict__ ws) {
  __shared__ __align__(16) char smem[K1_SZ];
  char*  xaz  = smem + K1_XA;
  float* hn2z = (float*)(smem + K1_HN);
  float* redz = (float*)(smem + K1_RED);

  const int t    = threadIdx.x;
  const int bid  = blockIdx.x;
  const int bimg = bid >> 5;
  const int hw0  = (bid & 31) << 7;
  const float4* xb4 = (const float4*)(x + (bimg << 18) + hw0);
  const uint4*  cbf = (const uint4*)(ws + WS_CBF);   // 4096 uint4 total

  // issue quarter-0 global loads first (overlap with x transpose)
  uint4 st[4];
  #pragma unroll
  for (int i = 0; i < 4; ++i) st[i] = cbf[i * 256 + t];

  // stage x tile: bf16 [row][d] swizzled + sum x^2
  float xsq = 0.f;
  {
    const int p  = t >> 3;                // d-pair 0..31
    const int r0 = (t & 7) << 4;          // row group
    #pragma unroll
    for (int j = 0; j < 4; ++j) {
      float4 A0 = xb4[((2 * p) << 10) + (r0 >> 2) + j];
      float4 A1 = xb4[((2 * p + 1) << 10) + (r0 >> 2) + j];
      const float* a0 = (const float*)&A0;
      const float* a1 = (const float*)&A1;
      #pragma unroll
      for (int u = 0; u < 4; ++u) {
        xsq = fmaf(a0[u], a0[u], xsq);
        xsq = fmaf(a1[u], a1[u], xsq);
        int r = r0 + (j << 2) + u;
        *(unsigned*)(xaz + r * 128 + ((p << 2) ^ swz(r))) = pack2(a0[u], a1[u]);
      }
    }
  }
  // hn2 to LDS
  hn2z[t]       = ((const float*)(ws + WS_HN2))[t];
  hn2z[t + 256] = ((const float*)(ws + WS_HN2))[t + 256];
  // write quarter 0 to LDS buf0
  #pragma unroll
  for (int i = 0; i < 4; ++i)
    *(uint4*)(smem + K1_CB0 + (i * 256 + t) * 16) = st[i];
  __syncthreads();

  const int lane = t & 63;
  const int wid  = t >> 6;
  const int lrow = lane & 15;
  const int lk2  = (lane >> 4) << 4;

  // A fragments persist in regs (2 row-subtiles x 2 k-steps)
  bf16x8 af[2][2];
  #pragma unroll
  for (int s = 0; s < 2; ++s) {
    int row = (wid << 5) + (s << 4) + lrow;
    int sw = swz(row);
    af[s][0] = *(const bf16x8*)(xaz + row * 128 + (lk2 ^ sw));
    af[s][1] = *(const bf16x8*)(xaz + row * 128 + ((lk2 ^ 64) ^ sw));
  }

  float bestv[2][4];
  int   besti[2][4];
  #pragma unroll
  for (int s = 0; s < 2; ++s)
    #pragma unroll
    for (int r = 0; r < 4; ++r) { bestv[s][r] = -3.0e38f; besti[s][r] = 0; }

  for (int q = 0; q < 4; ++q) {
    if (q < 3) {   // issue next-quarter loads (64B/thread, consumed this iter)
      #pragma unroll
      for (int i = 0; i < 4; ++i) st[i] = cbf[((q + 1) << 10) + i * 256 + t];
    }
    const char* cbb = smem + ((q & 1) ? K1_CB1 : K1_CB0);
    #pragma unroll
    for (int c8 = 0; c8 < 8; ++c8) {
      const bf16x8 b0 = *(const bf16x8*)(cbb + (c8 << 11) + (lane << 4));
      const bf16x8 b1 = *(const bf16x8*)(cbb + (c8 << 11) + 1024 + (lane << 4));
      const int nc = (q << 7) + (c8 << 4) + lrow;
      const float hv = hn2z[nc];
      #pragma unroll
      for (int s = 0; s < 2; ++s) {
        f32x4 acc = {hv, hv, hv, hv};
        acc = __builtin_amdgcn_mfma_f32_16x16x32_bf16(af[s][0], b0, acc, 0, 0, 0);
        acc = __builtin_amdgcn_mfma_f32_16x16x32_bf16(af[s][1], b1, acc, 0, 0, 0);
        #pragma unroll
        for (int r = 0; r < 4; ++r) {
          if (acc[r] > bestv[s][r]) { bestv[s][r] = acc[r]; besti[s][r] = nc; }
        }
      }
    }
    if (q < 3) {   // write into the other buffer (free since q-1's barrier)
      char* cbn = smem + ((q & 1) ? K1_CB0 : K1_CB1);
      #pragma unroll
      for (int i = 0; i < 4; ++i)
        *(uint4*)(cbn + (i * 256 + t) * 16) = st[i];
      __syncthreads();
    }
  }

  // cross-lane argmax over 16 column slots + idx store + loss partial
  unsigned short* wsid = (unsigned short*)(ws + WS_IDX);
  float vsum = 0.f;
  #pragma unroll
  for (int s = 0; s < 2; ++s) {
    #pragma unroll
    for (int r = 0; r < 4; ++r) {
      float v = bestv[s][r];
      int  id = besti[s][r];
      #pragma unroll
      for (int m = 1; m <= 8; m <<= 1) {
        float pv = __shfl_xor(v, m, 64);
        int   pi = __shfl_xor(id, m, 64);
        if (pv > v || (pv == v && pi < id)) { v = pv; id = pi; }
      }
      if (lrow == 0) {
        wsid[(bid << 7) + (wid << 5) + (s << 4) + ((lane >> 4) << 2) + r] =
            (unsigned short)id;
        vsum += v;
      }
    }
  }
  float lacc = xsq - 2.0f * vsum;       // SSD partial: ||x||^2 - 2*(dot - c2/2)
  #pragma unroll
  for (int m = 32; m; m >>= 1) lacc += __shfl_xor(lacc, m, 64);
  if (lane == 0) redz[wid] = lacc;
  __syncthreads();
  if (t == 0) ((float*)(ws + WS_RED))[bid] = redz[0] + redz[1] + redz[2] + redz[3];
}

// ================= k2: gather + transpose + store, loss finalize =================
__global__ void __launch_bounds__(256, 4)
vq_scatter(const float* __restrict__ cb, const char* __restrict__ ws,
           float* __restrict__ out) {
  __shared__ __align__(16) float qld[128 * 65 + 8];   // 33.3 KB
  const int t   = threadIdx.x;
  const int bid = blockIdx.x;

  // block 0: loss finalize (partials written by k1, prior kernel in stream)
  if (bid == 0) {
    const float* red = (const float*)(ws + WS_RED);
    float v = red[t] + red[t + 256] + red[t + 512] + red[t + 768];
    #pragma unroll
    for (int m = 32; m; m >>= 1) v += __shfl_xor(v, m, 64);
    if ((t & 63) == 0) qld[128 * 65 + (t >> 6)] = v;
  }

  // gather codebook rows (contiguous 128B per thread, L2-hot)
  {
    const int myrow = t >> 1;
    const int chh   = t & 1;
    const int myidx = (int)((const unsigned short*)(ws + WS_IDX))[(bid << 7) + myrow];
    const float4* cbr = (const float4*)cb + (myidx << 4) + (chh << 3);
    float* qrow = qld + myrow * 65 + (chh << 5);
    #pragma unroll
    for (int j = 0; j < 8; ++j) {
      float4 v = cbr[j];
      qrow[4 * j + 0] = v.x; qrow[4 * j + 1] = v.y;
      qrow[4 * j + 2] = v.z; qrow[4 * j + 3] = v.w;
    }
  }
  __syncthreads();
  if (bid == 0 && t == 0)
    out[0] = (qld[128 * 65 + 0] + qld[128 * 65 + 1] + qld[128 * 65 + 2] +
              qld[128 * 65 + 3]) * (1.25f / 8388608.0f);

  // coalesced NCHW store
  {
    const int bimg = bid >> 5;
    const int hw0  = (bid & 31) << 7;
    float* outq = out + 1 + (bimg << 18) + hw0;
    const int r = t & 127;
    const int dbase = t >> 7;
    #pragma unroll
    for (int i = 0; i < 32; ++i) {
      const int d = dbase + (i << 1);
      outq[(d << 12) + r] = qld[r * 65 + d];
    }
  }
}

extern "C" void kernel_launch(void* const* d_in, const int* in_sizes, int n_in,
                              void* d_out, int out_size, void* d_ws, size_t ws_size,
                              hipStream_t stream) {
  const float* x  = (const float*)d_in[0];   // 32*64*64*64 fp32 NCHW
  const float* cb = (const float*)d_in[1];   // 512*64 fp32
  float* out = (float*)d_out;
  char*  ws  = (char*)d_ws;                  // needs ~336 KB
  vq_prep<<<4, 128, 0, stream>>>(cb, ws);
  vq_argmin<<<1024, 256, 0, stream>>>(x, ws);
  vq_scatter<<<1024, 256, 0, stream>>>(cb, ws, out);
}

// Round 4
// 56.010 us; speedup vs baseline: 2.4971x; 2.4971x over previous
//
#include <hip/hip_runtime.h>
#include <hip/hip_bf16.h>

// VQ-VAE quantize: x[32,64,64,64] NCHW fp32, codebook[512,64] fp32.
// out[0] = 1.25*SSD/8388608 ; out[1..] = codebook[argmin] in NCHW.
// R4: single main kernel (R1 structure), 128-row tiles -> 4 blocks/CU.
// Codebook staged per-quarter in MFMA-fragment-linear LDS (0 bank conflicts),
// short-lived reg staging only (no cross-barrier global prefetch - R2/R3's
// 150+ MB scratch-spill signature came from that pattern).
// Loss fused: SSD = sum(x^2) - 2*sum(best score), score = dot - ||c||^2/2.

typedef __attribute__((ext_vector_type(8))) __bf16 bf16x8;
typedef __attribute__((ext_vector_type(4))) float f32x4;

// LDS layout (bytes)
#define K_XA   0        // 16384: bf16 x-tile [128 rows][64 d] swizzled
#define K_CB   16384    // 16384: codebook quarter, fragment-linear (8 ctiles)
#define K_HN   33280    // 2048:  -0.5*||c||^2 f32[512]
#define K_IDX  35328    // 512:   int idx[128]
#define K_RED  35840    // 16:    per-wave loss partials
#define K_SZ   35856
// phase-B overlay: f32 qld[128][65] = 33280 bytes over [0, 33280)

__device__ __forceinline__ unsigned f2b1(float f) {
  unsigned u = __float_as_uint(f);
  return (u + 0x7FFFu + ((u >> 16) & 1)) >> 16;   // RNE float->bf16 bits
}
__device__ __forceinline__ unsigned pack2(float lo, float hi) {
  return f2b1(lo) | (f2b1(hi) << 16);
}
__device__ __forceinline__ int swz(int row) {    // XOR swizzle, 16B granules
  return ((row & 7) ^ ((row >> 4) & 7)) << 4;
}

__global__ void __launch_bounds__(256, 4)
vq_main(const float* __restrict__ x, const float* __restrict__ cb,
        float* __restrict__ out, float* __restrict__ ws) {
  __shared__ __align__(16) char smem[K_SZ];
  char*  xaz  = smem + K_XA;
  char*  cbq  = smem + K_CB;
  float* hn2z = (float*)(smem + K_HN);
  int*   idxz = (int*)(smem + K_IDX);
  float* redz = (float*)(smem + K_RED);
  float* qld  = (float*)smem;             // phase-B overlay [128][65]

  const int t    = threadIdx.x;
  const int bid  = blockIdx.x;
  const int bimg = bid >> 5;
  const int hw0  = (bid & 31) << 7;
  const float4* xb4 = (const float4*)(x + (bimg << 18) + hw0);
  const float4* cb4 = (const float4*)cb;

  // ---- stage X tile: bf16 [row][d] swizzled + accumulate sum x^2 ----
  float xsq = 0.f;
  {
    const int p  = t >> 3;                // d-pair 0..31
    const int r0 = (t & 7) << 4;          // row group
    #pragma unroll
    for (int j = 0; j < 4; ++j) {
      float4 A0 = xb4[((2 * p) << 10) + (r0 >> 2) + j];
      float4 A1 = xb4[((2 * p + 1) << 10) + (r0 >> 2) + j];
      const float* a0 = (const float*)&A0;
      const float* a1 = (const float*)&A1;
      #pragma unroll
      for (int u = 0; u < 4; ++u) {
        xsq = fmaf(a0[u], a0[u], xsq);
        xsq = fmaf(a1[u], a1[u], xsq);
        int r = r0 + (j << 2) + u;
        *(unsigned*)(xaz + r * 128 + ((p << 2) ^ swz(r))) = pack2(a0[u], a1[u]);
      }
    }
  }
  // ---- hn2 for all 512 codes (L2-hot after first blocks) ----
  #pragma unroll
  for (int qq = 0; qq < 2; ++qq) {
    int n = t + (qq << 8);
    float s = 0.f;
    #pragma unroll
    for (int j = 0; j < 16; ++j) {
      float4 v = cb4[(n << 4) + j];
      s += v.x * v.x + v.y * v.y + v.z * v.z + v.w * v.w;
    }
    hn2z[n] = -0.5f * s;
  }
  // ---- stage codebook quarter 0 into fragment-linear LDS ----
  // fragment piece (ctile, kk, lane): code = ct*16+(lane&15),
  //   k = kk*32 + (lane>>4)*8 + e  -> 8 consecutive floats of the code row.
  {
    const int ct = t >> 5;
    #pragma unroll
    for (int i = 0; i < 4; ++i) {
      int p  = (t & 31) + (i << 5);        // 0..127 -> (kk, lane)
      int kk = p >> 6, ln = p & 63;
      int code = (ct << 4) + (ln & 15);
      int fo   = (code << 4) + (kk << 3) + ((ln >> 4) << 1);
      float4 a = cb4[fo], b = cb4[fo + 1];
      uint4 u = {pack2(a.x, a.y), pack2(a.z, a.w), pack2(b.x, b.y), pack2(b.z, b.w)};
      *(uint4*)(cbq + (((ct << 1) + kk) << 10) + (ln << 4)) = u;
    }
  }
  __syncthreads();

  const int lane = t & 63;
  const int wid  = t >> 6;
  const int lrow = lane & 15;
  const int lk2  = (lane >> 4) << 4;

  // A fragments persist in regs (2 row-subtiles x 2 k-steps)
  bf16x8 af[2][2];
  #pragma unroll
  for (int s = 0; s < 2; ++s) {
    int row = (wid << 5) + (s << 4) + lrow;
    int sw = swz(row);
    af[s][0] = *(const bf16x8*)(xaz + row * 128 + (lk2 ^ sw));
    af[s][1] = *(const bf16x8*)(xaz + row * 128 + ((lk2 ^ 64) ^ sw));
  }

  float bestv[2][4];
  int   besti[2][4];
  #pragma unroll
  for (int s = 0; s < 2; ++s)
    #pragma unroll
    for (int r = 0; r < 4; ++r) { bestv[s][r] = -3.0e38f; besti[s][r] = 0; }

  for (int q = 0; q < 4; ++q) {
    #pragma unroll
    for (int c8 = 0; c8 < 8; ++c8) {
      const bf16x8 b0 = *(const bf16x8*)(cbq + (c8 << 11) + (lane << 4));
      const bf16x8 b1 = *(const bf16x8*)(cbq + (c8 << 11) + 1024 + (lane << 4));
      const int nc = (q << 7) + (c8 << 4) + lrow;
      const float hv = hn2z[nc];
      #pragma unroll
      for (int s = 0; s < 2; ++s) {
        f32x4 acc = {hv, hv, hv, hv};
        acc = __builtin_amdgcn_mfma_f32_16x16x32_bf16(af[s][0], b0, acc, 0, 0, 0);
        acc = __builtin_amdgcn_mfma_f32_16x16x32_bf16(af[s][1], b1, acc, 0, 0, 0);
        #pragma unroll
        for (int r = 0; r < 4; ++r) {
          if (acc[r] > bestv[s][r]) { bestv[s][r] = acc[r]; besti[s][r] = nc; }
        }
      }
    }
    if (q < 3) {
      __syncthreads();                 // all waves done reading this quarter
      const int ct = t >> 5;
      #pragma unroll
      for (int i = 0; i < 4; ++i) {    // short-lived regs: load->cvt->store
        int p  = (t & 31) + (i << 5);
        int kk = p >> 6, ln = p & 63;
        int code = ((q + 1) << 7) + (ct << 4) + (ln & 15);
        int fo   = (code << 4) + (kk << 3) + ((ln >> 4) << 1);
        float4 a = cb4[fo], b = cb4[fo + 1];
        uint4 u = {pack2(a.x, a.y), pack2(a.z, a.w), pack2(b.x, b.y), pack2(b.z, b.w)};
        *(uint4*)(cbq + (((ct << 1) + kk) << 10) + (ln << 4)) = u;
      }
      __syncthreads();
    }
  }

  // ---- cross-lane argmax over the 16 code columns + loss partial ----
  float vsum = 0.f;
  #pragma unroll
  for (int s = 0; s < 2; ++s) {
    #pragma unroll
    for (int r = 0; r < 4; ++r) {
      float v = bestv[s][r];
      int  id = besti[s][r];
      #pragma unroll
      for (int m = 1; m <= 8; m <<= 1) {
        float pv = __shfl_xor(v, m, 64);
        int   pi = __shfl_xor(id, m, 64);
        if (pv > v || (pv == v && pi < id)) { v = pv; id = pi; }
      }
      if (lrow == 0) {
        idxz[(wid << 5) + (s << 4) + ((lane >> 4) << 2) + r] = id;
        vsum += v;
      }
    }
  }
  float lacc = xsq - 2.0f * vsum;
  #pragma unroll
  for (int m = 32; m; m >>= 1) lacc += __shfl_xor(lacc, m, 64);
  if (lane == 0) redz[wid] = lacc;
  __syncthreads();                      // idx+red ready; xaz/cbq now dead
  if (t == 0) ws[bid] = redz[0] + redz[1] + redz[2] + redz[3];

  // ---- phase B: gather code rows -> LDS transpose -> float4 NCHW store ----
  {
    const int myrow = t >> 1;
    const int chh   = t & 1;
    const int myidx = idxz[myrow];
    const float4* cbr = cb4 + (myidx << 4) + (chh << 3);
    float* qrow = qld + myrow * 65 + (chh << 5);
    #pragma unroll
    for (int j = 0; j < 8; ++j) {
      float4 v = cbr[j];
      qrow[4 * j + 0] = v.x; qrow[4 * j + 1] = v.y;
      qrow[4 * j + 2] = v.z; qrow[4 * j + 3] = v.w;
    }
  }
  __syncthreads();
  {
    float* outq = out + 1 + (bimg << 18) + hw0;
    const int r4 = (t & 31) << 2;       // row group of 4
    const int d0 = t >> 5;              // base d
    #pragma unroll
    for (int i = 0; i < 8; ++i) {
      const int d = d0 + (i << 3);
      float4 v = {qld[(r4 + 0) * 65 + d], qld[(r4 + 1) * 65 + d],
                  qld[(r4 + 2) * 65 + d], qld[(r4 + 3) * 65 + d]};
      *(float4*)(outq + (d << 12) + r4) = v;
    }
  }
}

__global__ void vq_finalize(const float* __restrict__ ws, float* __restrict__ out) {
  int t = threadIdx.x;
  __shared__ float red[4];
  float v = ws[t] + ws[t + 256] + ws[t + 512] + ws[t + 768];
  #pragma unroll
  for (int m = 32; m; m >>= 1) v += __shfl_xor(v, m, 64);
  if ((t & 63) == 0) red[t >> 6] = v;
  __syncthreads();
  if (t == 0) out[0] = (red[0] + red[1] + red[2] + red[3]) * (1.25f / 8388608.0f);
}

extern "C" void kernel_launch(void* const* d_in, const int* in_sizes, int n_in,
                              void* d_out, int out_size, void* d_ws, size_t ws_size,
                              hipStream_t stream) {
  const float* x  = (const float*)d_in[0];   // 32*64*64*64 fp32 NCHW
  const float* cb = (const float*)d_in[1];   // 512*64 fp32
  float* out = (float*)d_out;                // [0]=loss, [1..]=quantized NCHW
  float* ws  = (float*)d_ws;                 // 1024 loss partials
  vq_main<<<1024, 256, 0, stream>>>(x, cb, out, ws);
  vq_finalize<<<1, 256, 0, stream>>>(ws, out);
}